// Round 8
// baseline (409.512 us; speedup 1.0000x reference)
//
#include <hip/hip_runtime.h>

typedef __bf16 bf16_t;
typedef __bf16 bf16x8 __attribute__((ext_vector_type(8)));
typedef float f32x4 __attribute__((ext_vector_type(4)));

#define AS1 __attribute__((address_space(1)))
#define AS3 __attribute__((address_space(3)))

__device__ __forceinline__ void gload_lds16(const void* g, void* l) {
    __builtin_amdgcn_global_load_lds((const AS1 unsigned int*)g,
                                     (AS3 unsigned int*)l, 16, 0, 0);
}

__device__ __forceinline__ unsigned int pack2(float a, float b) {
    unsigned short lo = __builtin_bit_cast(unsigned short, (bf16_t)a);
    unsigned short hi = __builtin_bit_cast(unsigned short, (bf16_t)b);
    return (unsigned int)lo | ((unsigned int)hi << 16);
}

// ---------------------------------------------------------------- three_nn
// Value updates via fmed3/min (identical to select chains under the sorted
// invariant D1<=D2<=D3 -- field-proven r3/r4/r6/r7); index updates keep the
// exact select semantics (strict <, lowest index wins ties).
__device__ __forceinline__ void insdi(float d, int i,
                                      float& D1, int& I1, float& D2, int& I2,
                                      float& D3, int& I3) {
    const bool q1 = d < D1, q2 = d < D2, q3 = d < D3;
    I3 = q2 ? I2 : (q3 ? i : I3);
    I2 = q1 ? I1 : (q2 ? i : I2);
    I1 = q1 ? i : I1;
    D3 = __builtin_amdgcn_fmed3f(d, D2, D3);
    D2 = __builtin_amdgcn_fmed3f(d, D1, D2);
    D1 = fminf(d, D1);
}

// ------------------------------------------------- phase0 (fused front-end)
// blocks [0,1024)        : knn3 -- 64 queries/block, 8 waves x 256 knowns,
//                          4 contiguous 64-wide chains/wave, LDS merge.
// blocks [1024,3072)     : kf->kfT transpose, two 32x32 tiles per block.
// blocks [3072,3328)     : W1/W2 -> bf16 cast; 128 blocks per W.
// block  3328            : BN scale/shift prep.
__global__ __launch_bounds__(512) void phase0(
    const float* __restrict__ unknown, const float* __restrict__ known,
    int* __restrict__ idx3, float* __restrict__ w3,
    const float* __restrict__ kf, float* __restrict__ kfT,
    const float* __restrict__ W1, const float* __restrict__ W2,
    bf16_t* __restrict__ Wc1, bf16_t* __restrict__ Wc2,
    const float* g1, const float* b1, const float* m1, const float* v1,
    const float* g2, const float* b2, const float* m2, const float* v2,
    float* s1, float* t1, float* s2, float* t2)
{
    __shared__ __align__(16) char smem[45056];
    const int bx = blockIdx.x;
    const int tid = threadIdx.x;

    if (bx < 1024) {
        // ------------------------------------------------------------ knn3
        float4* kp = (float4*)smem;                                  // 32 KB
        float (*md)[64][3] = (float(*)[64][3])(smem + 32768);        // 6 KB
        int   (*mi)[64][3] = (int(*)[64][3])(smem + 32768 + 6144);   // 6 KB
        const int b = bx >> 7;
        const int px = bx & 127;
        const int lane = tid & 63;
        const int wv = tid >> 6;                 // 0..7

        const size_t kb = (size_t)b * 2048 * 3;
        for (int t = tid; t < 2048; t += 512) {
            kp[t] = make_float4(known[kb + t * 3 + 0], known[kb + t * 3 + 1],
                                known[kb + t * 3 + 2], 0.f);
        }
        __syncthreads();

        const int p = px * 64 + lane;
        const size_t qo = ((size_t)b * 8192 + p) * 3;
        const float qx = unknown[qo + 0];
        const float qy = unknown[qo + 1];
        const float qz = unknown[qo + 2];

        float d1[4], d2[4], d3[4];
        int   i1[4], i2[4], i3[4];
#pragma unroll
        for (int c = 0; c < 4; ++c) {
            d1[c] = 1e30f; d2[c] = 1e30f; d3[c] = 1e30f;
            i1[c] = 0;     i2[c] = 0;     i3[c] = 0;
        }

        const int jb = wv * 256;
#pragma unroll 2
        for (int t = 0; t < 64; ++t) {
#pragma unroll
            for (int c = 0; c < 4; ++c) {
                const int j = jb + c * 64 + t;   // chain c: contiguous block
                float4 k = kp[j];
                float dx = __fsub_rn(qx, k.x);
                float dy = __fsub_rn(qy, k.y);
                float dz = __fsub_rn(qz, k.z);
                float d = __fadd_rn(__fadd_rn(__fmul_rn(dx, dx),
                                              __fmul_rn(dy, dy)),
                                    __fmul_rn(dz, dz));
                insdi(d, j, d1[c], i1[c], d2[c], i2[c], d3[c], i3[c]);
            }
        }
        // merge 4 chains (ascending index ranges) -> wave-local top3
        float D1 = d1[0], D2 = d2[0], D3 = d3[0];
        int   I1 = i1[0], I2 = i2[0], I3 = i3[0];
#pragma unroll
        for (int c = 1; c < 4; ++c) {
            insdi(d1[c], i1[c], D1, I1, D2, I2, D3, I3);
            insdi(d2[c], i2[c], D1, I1, D2, I2, D3, I3);
            insdi(d3[c], i3[c], D1, I1, D2, I2, D3, I3);
        }
        md[wv][lane][0] = D1; md[wv][lane][1] = D2; md[wv][lane][2] = D3;
        mi[wv][lane][0] = I1; mi[wv][lane][1] = I2; mi[wv][lane][2] = I3;
        __syncthreads();

        if (tid < 64) {
            float F1 = md[0][tid][0], F2 = md[0][tid][1], F3 = md[0][tid][2];
            int   J1 = mi[0][tid][0], J2 = mi[0][tid][1], J3 = mi[0][tid][2];
#pragma unroll
            for (int w = 1; w < 8; ++w) {
                insdi(md[w][tid][0], mi[w][tid][0], F1, J1, F2, J2, F3, J3);
                insdi(md[w][tid][1], mi[w][tid][1], F1, J1, F2, J2, F3, J3);
                insdi(md[w][tid][2], mi[w][tid][2], F1, J1, F2, J2, F3, J3);
            }
            float r1 = __fdiv_rn(1.f, __fadd_rn(F1, 1e-8f));
            float r2 = __fdiv_rn(1.f, __fadd_rn(F2, 1e-8f));
            float r3 = __fdiv_rn(1.f, __fadd_rn(F3, 1e-8f));
            float s = __fadd_rn(__fadd_rn(r1, r2), r3);
            const int pp = px * 64 + tid;
            const size_t o = ((size_t)b * 8192 + pp) * 3;
            idx3[o + 0] = J1; idx3[o + 1] = J2; idx3[o + 2] = J3;
            w3[o + 0] = __fdiv_rn(r1, s);
            w3[o + 1] = __fdiv_rn(r2, s);
            w3[o + 2] = __fdiv_rn(r3, s);
        }
    } else if (bx < 3072) {
        // ------------------------------------------- kf -> kfT (two tiles)
        float (*tile)[32][33] = (float(*)[32][33])smem;
        const int u = bx - 1024;                 // 0..2047
        const int b = u >> 8;                    // 8
        const int rem = u & 255;
        const int ct = rem >> 5;                 // 8 c-tiles
        const int mt2 = rem & 31;                // 32 m-tile pairs
        const int s = tid >> 8;                  // sub-block 0/1
        const int t = tid & 255;
        const int m0 = (mt2 * 2 + s) * 32;
        const int c0 = ct * 32;
        const int tx = t & 31;
        const int ty = t >> 5;                   // 0..7
#pragma unroll
        for (int k = 0; k < 4; ++k) {
            const int c = c0 + ty + k * 8;
            tile[s][ty + k * 8][tx] = kf[((size_t)b * 256 + c) * 2048 + m0 + tx];
        }
        __syncthreads();
#pragma unroll
        for (int k = 0; k < 4; ++k) {
            const int m = m0 + ty + k * 8;
            kfT[((size_t)b * 2048 + m) * 256 + c0 + tx] = tile[s][tx][ty + k * 8];
        }
    } else if (bx < 3328) {
        // --------------------------------------------------- W -> bf16
        const int v = bx - 3072;                 // 0..255
        const float* Wsrc = (v < 128) ? W1 : W2;
        bf16_t* Wdst = (v < 128) ? Wc1 : Wc2;
        const size_t base = ((size_t)(v & 127) * 512 + tid) * 4;
        float4 w = *(const float4*)(Wsrc + base);
        unsigned int u0 = pack2(w.x, w.y);
        unsigned int u1 = pack2(w.z, w.w);
        *(uint2*)(Wdst + base) = make_uint2(u0, u1);
    } else {
        // --------------------------------------------------------- BN prep
        int i = tid;
        if (i < 512) {
            float s = __fdiv_rn(g1[i], __fsqrt_rn(__fadd_rn(v1[i], 1e-5f)));
            s1[i] = s;
            t1[i] = __fsub_rn(b1[i], __fmul_rn(m1[i], s));
            float q = __fdiv_rn(g2[i], __fsqrt_rn(__fadd_rn(v2[i], 1e-5f)));
            s2[i] = q;
            t2[i] = __fsub_rn(b2[i], __fmul_rn(m2[i], q));
        }
    }
}

// ------------------------------------- fused interp gather + uf transpose
__global__ __launch_bounds__(256) void interp_uf(
    const float* __restrict__ kfT, const int* __restrict__ idx3,
    const float* __restrict__ w3, const float* __restrict__ uf,
    bf16_t* __restrict__ XT, int b0, int p0, int P)
{
    __shared__ bf16_t tile[64][66];
    const int bl = blockIdx.y;
    const int bg = b0 + bl;
    const int gsplit = P >> 4;

    if ((int)blockIdx.x < gsplit) {
        const int pt = blockIdx.x * 16 + (threadIdx.x >> 4);
        const int ch = (threadIdx.x & 15) * 16;
        const int p = p0 + pt;

        const size_t ib = ((size_t)bg * 8192 + p) * 3;
        const int i0 = idx3[ib + 0] & 2047;
        const int i1 = idx3[ib + 1] & 2047;
        const int i2 = idx3[ib + 2] & 2047;
        const float w0 = w3[ib + 0], w1 = w3[ib + 1], w2 = w3[ib + 2];

        const float4* r0 = (const float4*)(kfT + ((size_t)bg * 2048 + i0) * 256 + ch);
        const float4* r1 = (const float4*)(kfT + ((size_t)bg * 2048 + i1) * 256 + ch);
        const float4* r2 = (const float4*)(kfT + ((size_t)bg * 2048 + i2) * 256 + ch);

        unsigned int u[8];
#pragma unroll
        for (int q = 0; q < 4; ++q) {
            float4 a = r0[q], bv = r1[q], c = r2[q];
            float v0 = w0 * a.x + w1 * bv.x + w2 * c.x;
            float v1 = w0 * a.y + w1 * bv.y + w2 * c.y;
            float v2 = w0 * a.z + w1 * bv.z + w2 * c.z;
            float v3 = w0 * a.w + w1 * bv.w + w2 * c.w;
            u[q * 2 + 0] = pack2(v0, v1);
            u[q * 2 + 1] = pack2(v2, v3);
        }
        uint4* dst = (uint4*)(XT + ((size_t)bl * P + pt) * 512 + ch);
        dst[0] = make_uint4(u[0], u[1], u[2], u[3]);
        dst[1] = make_uint4(u[4], u[5], u[6], u[7]);
    } else {
        const int u2 = blockIdx.x - gsplit;
        const int c0 = (u2 & 3) * 64;        // 0,64,128,192
        const int pc = (u2 >> 2) * 64;
        const int tid = threadIdx.x;
        const int pl = tid & 63;
        const int grp = tid >> 6;
        const int p = p0 + pc + pl;

#pragma unroll
        for (int cc = 0; cc < 16; ++cc) {
            const int lc = grp * 16 + cc;
            tile[lc][pl] = (bf16_t)uf[((size_t)bg * 256 + c0 + lc) * 8192 + p];
        }
        __syncthreads();

        const int pr = tid >> 2;
        const int cs = (tid & 3) * 16;
        unsigned int u[8];
#pragma unroll
        for (int q = 0; q < 8; ++q) {
            unsigned short lo = __builtin_bit_cast(unsigned short, tile[cs + 2 * q + 0][pr]);
            unsigned short hi = __builtin_bit_cast(unsigned short, tile[cs + 2 * q + 1][pr]);
            u[q] = (unsigned int)lo | ((unsigned int)hi << 16);
        }
        uint4* dst = (uint4*)(XT + ((size_t)bl * P + pc + pr) * 512 + 256 + c0 + cs);
        dst[0] = make_uint4(u[0], u[1], u[2], u[3]);
        dst[1] = make_uint4(u[4], u[5], u[6], u[7]);
    }
}

// --------------------------------------------------------------- GEMM + BN + ReLU
// D = A(M,K=512) x BT(Nrows,K=512)^T.
// LDS k-chunk XOR swizzle (both sides, field-proven r6/r7).
// XCD mapping (field-proven r7): x = point-tile, gridDim.x % 8 == 0 -> the 4
// blocks sharing a point-tile land on the same XCD L2.
// NEW (r8): minimum 2-phase pipeline -- double-buffered LDS; STAGE of tile
// k+1 issued BEFORE compute of tile k; ONE vmcnt(0)+barrier per K-step. The
// ~500cy load latency hides under the 16 MFMAs (was: full drain every step).
template <bool CHAN_IS_M, bool F32_OUT>
__global__ __launch_bounds__(256) void gemm_bt_bn_relu(
    const bf16_t* __restrict__ A, const bf16_t* __restrict__ BT,
    void* __restrict__ Cv,
    const float* __restrict__ scale, const float* __restrict__ shift,
    int ldC, size_t strideA, size_t strideB, size_t strideC, size_t cofs)
{
    __shared__ __align__(16) bf16_t As[2][128 * 32];
    __shared__ __align__(16) bf16_t Bs[2][128 * 32];

    const int b = blockIdx.z;
    const size_t cbase = cofs + (size_t)b * strideC;

    const int m0 = (CHAN_IS_M ? blockIdx.y : blockIdx.x) * 128;
    const int n0 = (CHAN_IS_M ? blockIdx.x : blockIdx.y) * 128;
    const bf16_t* Ab = A + (size_t)b * strideA + (size_t)m0 * 512;
    const bf16_t* Bb = BT + (size_t)b * strideB + (size_t)n0 * 512;

    const int tid = threadIdx.x;
    const int lane = tid & 63;
    const int wave = tid >> 6;
    const int wm = (wave & 1) * 64;
    const int wn = (wave >> 1) * 64;

    // staging: chunk ch -> LDS byte ch*16 (linear); global source k-chunk XORed
    const int ch0 = tid, ch1 = tid + 256;
    const int row0 = ch0 >> 2, row1 = ch1 >> 2;
    const size_t ga0 = (size_t)row0 * 512 + (size_t)((ch0 & 3) ^ ((row0 >> 1) & 3)) * 8;
    const size_t ga1 = (size_t)row1 * 512 + (size_t)((ch1 & 3) ^ ((row1 >> 1) & 3)) * 8;

    const int row_a = lane & 15;
    const int kq = lane >> 4;                    // k-chunk 0..3
    const int sw = (row_a >> 1) & 3;
    const int kswz = (kq ^ sw) * 8;              // element offset in LDS row
    const int col = lane & 15;
    const int rbase = (lane >> 4) * 4;

    f32x4 acc[4][4] = {};

    // prologue: stage tile 0 into buffer 0
    gload_lds16(Ab + ga0, As[0] + (size_t)ch0 * 8);
    gload_lds16(Ab + ga1, As[0] + (size_t)ch1 * 8);
    gload_lds16(Bb + ga0, Bs[0] + (size_t)ch0 * 8);
    gload_lds16(Bb + ga1, Bs[0] + (size_t)ch1 * 8);
    asm volatile("s_waitcnt vmcnt(0)" ::: "memory");
    __syncthreads();

    int cur = 0;
    for (int kt = 0; kt < 512; kt += 32) {
        const int nxt = cur ^ 1;
        if (kt + 32 < 512) {                     // issue next-tile loads EARLY
            gload_lds16(Ab + ga0 + kt + 32, As[nxt] + (size_t)ch0 * 8);
            gload_lds16(Ab + ga1 + kt + 32, As[nxt] + (size_t)ch1 * 8);
            gload_lds16(Bb + ga0 + kt + 32, Bs[nxt] + (size_t)ch0 * 8);
            gload_lds16(Bb + ga1 + kt + 32, Bs[nxt] + (size_t)ch1 * 8);
        }

        bf16x8 af[4], bfr[4];
#pragma unroll
        for (int i = 0; i < 4; ++i)
            af[i] = *(const bf16x8*)(As[cur] + (size_t)(wm + i * 16 + row_a) * 32 + kswz);
#pragma unroll
        for (int j = 0; j < 4; ++j)
            bfr[j] = *(const bf16x8*)(Bs[cur] + (size_t)(wn + j * 16 + row_a) * 32 + kswz);
#pragma unroll
        for (int i = 0; i < 4; ++i)
#pragma unroll
            for (int j = 0; j < 4; ++j)
                acc[i][j] = __builtin_amdgcn_mfma_f32_16x16x32_bf16(
                    af[i], bfr[j], acc[i][j], 0, 0, 0);

        asm volatile("s_waitcnt vmcnt(0)" ::: "memory");  // next tile landed
        __syncthreads();
        cur = nxt;
    }

#pragma unroll
    for (int i = 0; i < 4; ++i) {
#pragma unroll
        for (int j = 0; j < 4; ++j) {
            const int mb = m0 + wm + i * 16 + rbase;
            const int nn = n0 + wn + j * 16 + col;
            float sc = 0.f, sh = 0.f;
            if (!CHAN_IS_M) { sc = scale[nn]; sh = shift[nn]; }
#pragma unroll
            for (int r = 0; r < 4; ++r) {
                const int mm = mb + r;
                float s = CHAN_IS_M ? scale[mm] : sc;
                float t = CHAN_IS_M ? shift[mm] : sh;
                float v = fmaxf(acc[i][j][r] * s + t, 0.0f);
                const size_t ci = cbase + (size_t)mm * (size_t)ldC + nn;
                if (F32_OUT) ((float*)Cv)[ci] = v;
                else         ((bf16_t*)Cv)[ci] = (bf16_t)v;
            }
        }
    }
}

// ---------------------------------------------------------------- launch
extern "C" void kernel_launch(void* const* d_in, const int* in_sizes, int n_in,
                              void* d_out, int out_size, void* d_ws, size_t ws_size,
                              hipStream_t stream) {
    (void)in_sizes; (void)n_in; (void)out_size;
    const float* unknown  = (const float*)d_in[0];
    const float* known    = (const float*)d_in[1];
    const float* unknow_f = (const float*)d_in[2];
    const float* known_f  = (const float*)d_in[3];
    const float* W1       = (const float*)d_in[4];
    const float* g1 = (const float*)d_in[5]; const float* b1 = (const float*)d_in[6];
    const float* m1 = (const float*)d_in[7]; const float* v1 = (const float*)d_in[8];
    const float* W2       = (const float*)d_in[9];
    const float* g2 = (const float*)d_in[10]; const float* b2 = (const float*)d_in[11];
    const float* m2 = (const float*)d_in[12]; const float* v2 = (const float*)d_in[13];

    char* ws = (char*)d_ws;
    float* s1 = (float*)(ws + 0);
    float* t1 = s1 + 512;
    float* s2 = s1 + 1024;
    float* t2 = s1 + 1536;
    int*    idx3 = (int*)(ws + 16384);                 // 768 KB
    float*  w3   = (float*)(ws + 16384 + 786432);      // 768 KB -> ends 1589248
    bf16_t* Wc1  = (bf16_t*)(ws + 1589248);            // 512 KB
    bf16_t* Wc2  = (bf16_t*)(ws + 2113536);            // 512 KB -> ends 2637824
    float*  kfT  = (float*)(ws + (3u << 20));          // 16 MB (8,2048,256) f32
    const size_t FIXED = 20u << 20;                    // 20 MB fixed region

    // scratch tiers: XT+HT cost 2048 B per (batch,point)
    size_t avail = (ws_size > FIXED) ? (ws_size - FIXED) : 0;
    size_t pts = avail / 2048;
    int nb, P;
    if (pts >= 65536)      { nb = 8; P = 8192; }
    else if (pts >= 8192)  { nb = (int)(pts / 8192); P = 8192; }
    else {
        nb = 1;
        P = (int)((pts / 128) * 128);
        if (P < 128) P = 128;
        if (P > 8192) P = 8192;
    }
    bf16_t* XT = (bf16_t*)(ws + FIXED);
    bf16_t* HT = XT + (size_t)nb * P * 512;

    phase0<<<3329, 512, 0, stream>>>(unknown, known, idx3, w3,
                                     known_f, kfT, W1, W2, Wc1, Wc2,
                                     g1, b1, m1, v1, g2, b2, m2, v2,
                                     s1, t1, s2, t2);

    for (int b0 = 0; b0 < 8; b0 += nb) {
        const int cur = (8 - b0 < nb) ? (8 - b0) : nb;
        for (int p0 = 0; p0 < 8192; p0 += P) {
            const int cp = (8192 - p0 < P) ? (8192 - p0) : P;

            interp_uf<<<dim3(cp / 8, cur), 256, 0, stream>>>(
                kfT, idx3, w3, unknow_f, XT, b0, p0, cp);

            // GEMM1: HT[p][o] = relu(s1[o]*(XT x Wc1^T)+t1[o]); bf16 out
            gemm_bt_bn_relu<false, false><<<dim3(cp / 128, 4, cur), 256, 0, stream>>>(
                XT, Wc1, HT, s1, t1, 512,
                (size_t)cp * 512, (size_t)0, (size_t)cp * 512, (size_t)0);

            // GEMM2: OUT[o][p0+n] = relu(s2[o]*(Wc2 x HT^T)+t2[o]); f32 out
            gemm_bt_bn_relu<true, true><<<dim3(cp / 128, 4, cur), 256, 0, stream>>>(
                Wc2, HT, d_out, s2, t2, 8192,
                (size_t)0, (size_t)cp * 512, (size_t)512 * 8192,
                (size_t)b0 * 512 * 8192 + p0);
        }
    }
}

// Round 9
// 397.754 us; speedup vs baseline: 1.0296x; 1.0296x over previous
//
#include <hip/hip_runtime.h>

typedef __bf16 bf16_t;
typedef __bf16 bf16x8 __attribute__((ext_vector_type(8)));
typedef float f32x4 __attribute__((ext_vector_type(4)));

#define AS1 __attribute__((address_space(1)))
#define AS3 __attribute__((address_space(3)))

__device__ __forceinline__ void gload_lds16(const void* g, void* l) {
    __builtin_amdgcn_global_load_lds((const AS1 unsigned int*)g,
                                     (AS3 unsigned int*)l, 16, 0, 0);
}

__device__ __forceinline__ unsigned int pack2(float a, float b) {
    unsigned short lo = __builtin_bit_cast(unsigned short, (bf16_t)a);
    unsigned short hi = __builtin_bit_cast(unsigned short, (bf16_t)b);
    return (unsigned int)lo | ((unsigned int)hi << 16);
}

// ---------------------------------------------------------------- three_nn
// Value updates via fmed3/min (identical to select chains under the sorted
// invariant D1<=D2<=D3 -- field-proven r3/r4/r6/r7); index updates keep the
// exact select semantics (strict <, lowest index wins ties).
__device__ __forceinline__ void insdi(float d, int i,
                                      float& D1, int& I1, float& D2, int& I2,
                                      float& D3, int& I3) {
    const bool q1 = d < D1, q2 = d < D2, q3 = d < D3;
    I3 = q2 ? I2 : (q3 ? i : I3);
    I2 = q1 ? I1 : (q2 ? i : I2);
    I1 = q1 ? i : I1;
    D3 = __builtin_amdgcn_fmed3f(d, D2, D3);
    D2 = __builtin_amdgcn_fmed3f(d, D1, D2);
    D1 = fminf(d, D1);
}

// ------------------------------------------------- phase0 (fused front-end)
// blocks [0,1024)        : knn3 -- 64 queries/block, 8 waves x 256 knowns,
//                          4 contiguous 64-wide chains/wave, LDS merge.
// blocks [1024,3072)     : kf->kfT transpose, two 32x32 tiles per block.
// blocks [3072,3328)     : W1/W2 -> bf16 cast; 128 blocks per W.
// block  3328            : BN scale/shift prep.
__global__ __launch_bounds__(512) void phase0(
    const float* __restrict__ unknown, const float* __restrict__ known,
    int* __restrict__ idx3, float* __restrict__ w3,
    const float* __restrict__ kf, float* __restrict__ kfT,
    const float* __restrict__ W1, const float* __restrict__ W2,
    bf16_t* __restrict__ Wc1, bf16_t* __restrict__ Wc2,
    const float* g1, const float* b1, const float* m1, const float* v1,
    const float* g2, const float* b2, const float* m2, const float* v2,
    float* s1, float* t1, float* s2, float* t2)
{
    __shared__ __align__(16) char smem[45056];
    const int bx = blockIdx.x;
    const int tid = threadIdx.x;

    if (bx < 1024) {
        // ------------------------------------------------------------ knn3
        float4* kp = (float4*)smem;                                  // 32 KB
        float (*md)[64][3] = (float(*)[64][3])(smem + 32768);        // 6 KB
        int   (*mi)[64][3] = (int(*)[64][3])(smem + 32768 + 6144);   // 6 KB
        const int b = bx >> 7;
        const int px = bx & 127;
        const int lane = tid & 63;
        const int wv = tid >> 6;                 // 0..7

        const size_t kb = (size_t)b * 2048 * 3;
        for (int t = tid; t < 2048; t += 512) {
            kp[t] = make_float4(known[kb + t * 3 + 0], known[kb + t * 3 + 1],
                                known[kb + t * 3 + 2], 0.f);
        }
        __syncthreads();

        const int p = px * 64 + lane;
        const size_t qo = ((size_t)b * 8192 + p) * 3;
        const float qx = unknown[qo + 0];
        const float qy = unknown[qo + 1];
        const float qz = unknown[qo + 2];

        float d1[4], d2[4], d3[4];
        int   i1[4], i2[4], i3[4];
#pragma unroll
        for (int c = 0; c < 4; ++c) {
            d1[c] = 1e30f; d2[c] = 1e30f; d3[c] = 1e30f;
            i1[c] = 0;     i2[c] = 0;     i3[c] = 0;
        }

        const int jb = wv * 256;
#pragma unroll 2
        for (int t = 0; t < 64; ++t) {
#pragma unroll
            for (int c = 0; c < 4; ++c) {
                const int j = jb + c * 64 + t;   // chain c: contiguous block
                float4 k = kp[j];
                float dx = __fsub_rn(qx, k.x);
                float dy = __fsub_rn(qy, k.y);
                float dz = __fsub_rn(qz, k.z);
                float d = __fadd_rn(__fadd_rn(__fmul_rn(dx, dx),
                                              __fmul_rn(dy, dy)),
                                    __fmul_rn(dz, dz));
                insdi(d, j, d1[c], i1[c], d2[c], i2[c], d3[c], i3[c]);
            }
        }
        // merge 4 chains (ascending index ranges) -> wave-local top3
        float D1 = d1[0], D2 = d2[0], D3 = d3[0];
        int   I1 = i1[0], I2 = i2[0], I3 = i3[0];
#pragma unroll
        for (int c = 1; c < 4; ++c) {
            insdi(d1[c], i1[c], D1, I1, D2, I2, D3, I3);
            insdi(d2[c], i2[c], D1, I1, D2, I2, D3, I3);
            insdi(d3[c], i3[c], D1, I1, D2, I2, D3, I3);
        }
        md[wv][lane][0] = D1; md[wv][lane][1] = D2; md[wv][lane][2] = D3;
        mi[wv][lane][0] = I1; mi[wv][lane][1] = I2; mi[wv][lane][2] = I3;
        __syncthreads();

        if (tid < 64) {
            float F1 = md[0][tid][0], F2 = md[0][tid][1], F3 = md[0][tid][2];
            int   J1 = mi[0][tid][0], J2 = mi[0][tid][1], J3 = mi[0][tid][2];
#pragma unroll
            for (int w = 1; w < 8; ++w) {
                insdi(md[w][tid][0], mi[w][tid][0], F1, J1, F2, J2, F3, J3);
                insdi(md[w][tid][1], mi[w][tid][1], F1, J1, F2, J2, F3, J3);
                insdi(md[w][tid][2], mi[w][tid][2], F1, J1, F2, J2, F3, J3);
            }
            float r1 = __fdiv_rn(1.f, __fadd_rn(F1, 1e-8f));
            float r2 = __fdiv_rn(1.f, __fadd_rn(F2, 1e-8f));
            float r3 = __fdiv_rn(1.f, __fadd_rn(F3, 1e-8f));
            float s = __fadd_rn(__fadd_rn(r1, r2), r3);
            const int pp = px * 64 + tid;
            const size_t o = ((size_t)b * 8192 + pp) * 3;
            idx3[o + 0] = J1; idx3[o + 1] = J2; idx3[o + 2] = J3;
            w3[o + 0] = __fdiv_rn(r1, s);
            w3[o + 1] = __fdiv_rn(r2, s);
            w3[o + 2] = __fdiv_rn(r3, s);
        }
    } else if (bx < 3072) {
        // ------------------------------------------- kf -> kfT (two tiles)
        float (*tile)[32][33] = (float(*)[32][33])smem;
        const int u = bx - 1024;                 // 0..2047
        const int b = u >> 8;                    // 8
        const int rem = u & 255;
        const int ct = rem >> 5;                 // 8 c-tiles
        const int mt2 = rem & 31;                // 32 m-tile pairs
        const int s = tid >> 8;                  // sub-block 0/1
        const int t = tid & 255;
        const int m0 = (mt2 * 2 + s) * 32;
        const int c0 = ct * 32;
        const int tx = t & 31;
        const int ty = t >> 5;                   // 0..7
#pragma unroll
        for (int k = 0; k < 4; ++k) {
            const int c = c0 + ty + k * 8;
            tile[s][ty + k * 8][tx] = kf[((size_t)b * 256 + c) * 2048 + m0 + tx];
        }
        __syncthreads();
#pragma unroll
        for (int k = 0; k < 4; ++k) {
            const int m = m0 + ty + k * 8;
            kfT[((size_t)b * 2048 + m) * 256 + c0 + tx] = tile[s][tx][ty + k * 8];
        }
    } else if (bx < 3328) {
        // --------------------------------------------------- W -> bf16
        const int v = bx - 3072;                 // 0..255
        const float* Wsrc = (v < 128) ? W1 : W2;
        bf16_t* Wdst = (v < 128) ? Wc1 : Wc2;
        const size_t base = ((size_t)(v & 127) * 512 + tid) * 4;
        float4 w = *(const float4*)(Wsrc + base);
        unsigned int u0 = pack2(w.x, w.y);
        unsigned int u1 = pack2(w.z, w.w);
        *(uint2*)(Wdst + base) = make_uint2(u0, u1);
    } else {
        // --------------------------------------------------------- BN prep
        int i = tid;
        if (i < 512) {
            float s = __fdiv_rn(g1[i], __fsqrt_rn(__fadd_rn(v1[i], 1e-5f)));
            s1[i] = s;
            t1[i] = __fsub_rn(b1[i], __fmul_rn(m1[i], s));
            float q = __fdiv_rn(g2[i], __fsqrt_rn(__fadd_rn(v2[i], 1e-5f)));
            s2[i] = q;
            t2[i] = __fsub_rn(b2[i], __fmul_rn(m2[i], q));
        }
    }
}

// ------------------------------------- fused interp gather + uf transpose
__global__ __launch_bounds__(256) void interp_uf(
    const float* __restrict__ kfT, const int* __restrict__ idx3,
    const float* __restrict__ w3, const float* __restrict__ uf,
    bf16_t* __restrict__ XT, int b0, int p0, int P)
{
    __shared__ bf16_t tile[64][66];
    const int bl = blockIdx.y;
    const int bg = b0 + bl;
    const int gsplit = P >> 4;

    if ((int)blockIdx.x < gsplit) {
        const int pt = blockIdx.x * 16 + (threadIdx.x >> 4);
        const int ch = (threadIdx.x & 15) * 16;
        const int p = p0 + pt;

        const size_t ib = ((size_t)bg * 8192 + p) * 3;
        const int i0 = idx3[ib + 0] & 2047;
        const int i1 = idx3[ib + 1] & 2047;
        const int i2 = idx3[ib + 2] & 2047;
        const float w0 = w3[ib + 0], w1 = w3[ib + 1], w2 = w3[ib + 2];

        const float4* r0 = (const float4*)(kfT + ((size_t)bg * 2048 + i0) * 256 + ch);
        const float4* r1 = (const float4*)(kfT + ((size_t)bg * 2048 + i1) * 256 + ch);
        const float4* r2 = (const float4*)(kfT + ((size_t)bg * 2048 + i2) * 256 + ch);

        unsigned int u[8];
#pragma unroll
        for (int q = 0; q < 4; ++q) {
            float4 a = r0[q], bv = r1[q], c = r2[q];
            float v0 = w0 * a.x + w1 * bv.x + w2 * c.x;
            float v1 = w0 * a.y + w1 * bv.y + w2 * c.y;
            float v2 = w0 * a.z + w1 * bv.z + w2 * c.z;
            float v3 = w0 * a.w + w1 * bv.w + w2 * c.w;
            u[q * 2 + 0] = pack2(v0, v1);
            u[q * 2 + 1] = pack2(v2, v3);
        }
        uint4* dst = (uint4*)(XT + ((size_t)bl * P + pt) * 512 + ch);
        dst[0] = make_uint4(u[0], u[1], u[2], u[3]);
        dst[1] = make_uint4(u[4], u[5], u[6], u[7]);
    } else {
        const int u2 = blockIdx.x - gsplit;
        const int c0 = (u2 & 3) * 64;        // 0,64,128,192
        const int pc = (u2 >> 2) * 64;
        const int tid = threadIdx.x;
        const int pl = tid & 63;
        const int grp = tid >> 6;
        const int p = p0 + pc + pl;

#pragma unroll
        for (int cc = 0; cc < 16; ++cc) {
            const int lc = grp * 16 + cc;
            tile[lc][pl] = (bf16_t)uf[((size_t)bg * 256 + c0 + lc) * 8192 + p];
        }
        __syncthreads();

        const int pr = tid >> 2;
        const int cs = (tid & 3) * 16;
        unsigned int u[8];
#pragma unroll
        for (int q = 0; q < 8; ++q) {
            unsigned short lo = __builtin_bit_cast(unsigned short, tile[cs + 2 * q + 0][pr]);
            unsigned short hi = __builtin_bit_cast(unsigned short, tile[cs + 2 * q + 1][pr]);
            u[q] = (unsigned int)lo | ((unsigned int)hi << 16);
        }
        uint4* dst = (uint4*)(XT + ((size_t)bl * P + pc + pr) * 512 + 256 + c0 + cs);
        dst[0] = make_uint4(u[0], u[1], u[2], u[3]);
        dst[1] = make_uint4(u[4], u[5], u[6], u[7]);
    }
}

// --------------------------------------------------------------- GEMM + BN + ReLU
// D = A(M,K=512) x BT(Nrows,K=512)^T.
// XCD mapping (field-proven r7): x = point-tile, gridDim.x % 8 == 0 -> the 4
// blocks sharing a point-tile land on the same XCD L2.
// r9: BK=64 (8 drain-barriers instead of 16; r8 showed pipelining across the
// barrier is null-to-negative, so amortize the drain instead). LDS rows are
// now 128B -> XOR swizzle chunk^=(row&7): a 16-lane fragment-read group hits
// 8 distinct 16B bank slots (rows 8..15 repeat = free 2-way). Same involution
// on the staging source (linear global_load_lds dest, rule-21 pattern).
template <bool CHAN_IS_M, bool F32_OUT>
__global__ __launch_bounds__(256) void gemm_bt_bn_relu(
    const bf16_t* __restrict__ A, const bf16_t* __restrict__ BT,
    void* __restrict__ Cv,
    const float* __restrict__ scale, const float* __restrict__ shift,
    int ldC, size_t strideA, size_t strideB, size_t strideC, size_t cofs)
{
    __shared__ __align__(16) bf16_t As[128 * 64];
    __shared__ __align__(16) bf16_t Bs[128 * 64];

    const int b = blockIdx.z;
    const size_t cbase = cofs + (size_t)b * strideC;

    const int m0 = (CHAN_IS_M ? blockIdx.y : blockIdx.x) * 128;
    const int n0 = (CHAN_IS_M ? blockIdx.x : blockIdx.y) * 128;
    const bf16_t* Ab = A + (size_t)b * strideA + (size_t)m0 * 512;
    const bf16_t* Bb = BT + (size_t)b * strideB + (size_t)n0 * 512;

    const int tid = threadIdx.x;
    const int lane = tid & 63;
    const int wave = tid >> 6;
    const int wm = (wave & 1) * 64;
    const int wn = (wave >> 1) * 64;

    // staging: 1024 16B chunks per matrix per K-step; thread covers chunks
    // tid, tid+256, tid+512, tid+768 (LDS-linear). Global chunk col XORed.
    size_t goff[4];
#pragma unroll
    for (int q = 0; q < 4; ++q) {
        const int ck = tid + q * 256;
        const int row = ck >> 3;
        const int c = ck & 7;
        goff[q] = (size_t)row * 512 + (size_t)((c ^ (row & 7)) * 8);
    }

    const int row_a = lane & 15;
    const int kq = lane >> 4;                    // 16B chunk 0..3 within half
    const int rsw = row_a & 7;
    const int col = lane & 15;
    const int rbase = (lane >> 4) * 4;

    f32x4 acc[4][4] = {};

    for (int kt = 0; kt < 512; kt += 64) {
#pragma unroll
        for (int q = 0; q < 4; ++q) {
            gload_lds16(Ab + goff[q] + kt, As + (size_t)(tid + q * 256) * 8);
            gload_lds16(Bb + goff[q] + kt, Bs + (size_t)(tid + q * 256) * 8);
        }
        __builtin_amdgcn_s_waitcnt(0);
        __syncthreads();

#pragma unroll
        for (int h = 0; h < 2; ++h) {
            const int csel = ((h * 4 + kq) ^ rsw) * 8;   // element offset in row
            bf16x8 af[4], bfr[4];
#pragma unroll
            for (int i = 0; i < 4; ++i)
                af[i] = *(const bf16x8*)(As + (size_t)(wm + i * 16 + row_a) * 64 + csel);
#pragma unroll
            for (int j = 0; j < 4; ++j)
                bfr[j] = *(const bf16x8*)(Bs + (size_t)(wn + j * 16 + row_a) * 64 + csel);
#pragma unroll
            for (int i = 0; i < 4; ++i)
#pragma unroll
                for (int j = 0; j < 4; ++j)
                    acc[i][j] = __builtin_amdgcn_mfma_f32_16x16x32_bf16(
                        af[i], bfr[j], acc[i][j], 0, 0, 0);
        }
        __syncthreads();
    }

#pragma unroll
    for (int i = 0; i < 4; ++i) {
#pragma unroll
        for (int j = 0; j < 4; ++j) {
            const int mb = m0 + wm + i * 16 + rbase;
            const int nn = n0 + wn + j * 16 + col;
            float sc = 0.f, sh = 0.f;
            if (!CHAN_IS_M) { sc = scale[nn]; sh = shift[nn]; }
#pragma unroll
            for (int r = 0; r < 4; ++r) {
                const int mm = mb + r;
                float s = CHAN_IS_M ? scale[mm] : sc;
                float t = CHAN_IS_M ? shift[mm] : sh;
                float v = fmaxf(acc[i][j][r] * s + t, 0.0f);
                const size_t ci = cbase + (size_t)mm * (size_t)ldC + nn;
                if (F32_OUT) {
                    // output is never re-read -> keep it out of L2
                    __builtin_nontemporal_store(v, (float*)Cv + ci);
                } else {
                    ((bf16_t*)Cv)[ci] = (bf16_t)v;
                }
            }
        }
    }
}

// ---------------------------------------------------------------- launch
extern "C" void kernel_launch(void* const* d_in, const int* in_sizes, int n_in,
                              void* d_out, int out_size, void* d_ws, size_t ws_size,
                              hipStream_t stream) {
    (void)in_sizes; (void)n_in; (void)out_size;
    const float* unknown  = (const float*)d_in[0];
    const float* known    = (const float*)d_in[1];
    const float* unknow_f = (const float*)d_in[2];
    const float* known_f  = (const float*)d_in[3];
    const float* W1       = (const float*)d_in[4];
    const float* g1 = (const float*)d_in[5]; const float* b1 = (const float*)d_in[6];
    const float* m1 = (const float*)d_in[7]; const float* v1 = (const float*)d_in[8];
    const float* W2       = (const float*)d_in[9];
    const float* g2 = (const float*)d_in[10]; const float* b2 = (const float*)d_in[11];
    const float* m2 = (const float*)d_in[12]; const float* v2 = (const float*)d_in[13];

    char* ws = (char*)d_ws;
    float* s1 = (float*)(ws + 0);
    float* t1 = s1 + 512;
    float* s2 = s1 + 1024;
    float* t2 = s1 + 1536;
    int*    idx3 = (int*)(ws + 16384);                 // 768 KB
    float*  w3   = (float*)(ws + 16384 + 786432);      // 768 KB -> ends 1589248
    bf16_t* Wc1  = (bf16_t*)(ws + 1589248);            // 512 KB
    bf16_t* Wc2  = (bf16_t*)(ws + 2113536);            // 512 KB -> ends 2637824
    float*  kfT  = (float*)(ws + (3u << 20));          // 16 MB (8,2048,256) f32
    const size_t FIXED = 20u << 20;                    // 20 MB fixed region

    // scratch tiers: XT+HT cost 2048 B per (batch,point)
    size_t avail = (ws_size > FIXED) ? (ws_size - FIXED) : 0;
    size_t pts = avail / 2048;
    int nb, P;
    if (pts >= 65536)      { nb = 8; P = 8192; }
    else if (pts >= 8192)  { nb = (int)(pts / 8192); P = 8192; }
    else {
        nb = 1;
        P = (int)((pts / 128) * 128);
        if (P < 128) P = 128;
        if (P > 8192) P = 8192;
    }
    bf16_t* XT = (bf16_t*)(ws + FIXED);
    bf16_t* HT = XT + (size_t)nb * P * 512;

    phase0<<<3329, 512, 0, stream>>>(unknown, known, idx3, w3,
                                     known_f, kfT, W1, W2, Wc1, Wc2,
                                     g1, b1, m1, v1, g2, b2, m2, v2,
                                     s1, t1, s2, t2);

    for (int b0 = 0; b0 < 8; b0 += nb) {
        const int cur = (8 - b0 < nb) ? (8 - b0) : nb;
        for (int p0 = 0; p0 < 8192; p0 += P) {
            const int cp = (8192 - p0 < P) ? (8192 - p0) : P;

            interp_uf<<<dim3(cp / 8, cur), 256, 0, stream>>>(
                kfT, idx3, w3, unknow_f, XT, b0, p0, cp);

            // GEMM1: HT[p][o] = relu(s1[o]*(XT x Wc1^T)+t1[o]); bf16 out
            gemm_bt_bn_relu<false, false><<<dim3(cp / 128, 4, cur), 256, 0, stream>>>(
                XT, Wc1, HT, s1, t1, 512,
                (size_t)cp * 512, (size_t)0, (size_t)cp * 512, (size_t)0);

            // GEMM2: OUT[o][p0+n] = relu(s2[o]*(Wc2 x HT^T)+t2[o]); f32 out
            gemm_bt_bn_relu<true, true><<<dim3(cp / 128, 4, cur), 256, 0, stream>>>(
                Wc2, HT, d_out, s2, t2, 8192,
                (size_t)0, (size_t)cp * 512, (size_t)512 * 8192,
                (size_t)b0 * 512 * 8192 + p0);
        }
    }
}

// Round 12
// 388.572 us; speedup vs baseline: 1.0539x; 1.0236x over previous
//
#include <hip/hip_runtime.h>

typedef __bf16 bf16_t;
typedef __bf16 bf16x8 __attribute__((ext_vector_type(8)));
typedef float f32x4 __attribute__((ext_vector_type(4)));

#define AS1 __attribute__((address_space(1)))
#define AS3 __attribute__((address_space(3)))

__device__ __forceinline__ void gload_lds16(const void* g, void* l) {
    __builtin_amdgcn_global_load_lds((const AS1 unsigned int*)g,
                                     (AS3 unsigned int*)l, 16, 0, 0);
}

__device__ __forceinline__ unsigned int pack2(float a, float b) {
    unsigned short lo = __builtin_bit_cast(unsigned short, (bf16_t)a);
    unsigned short hi = __builtin_bit_cast(unsigned short, (bf16_t)b);
    return (unsigned int)lo | ((unsigned int)hi << 16);
}

// ---------------------------------------------------------------- three_nn
// Value updates via fmed3/min (identical to select chains under the sorted
// invariant D1<=D2<=D3 -- field-proven r3..r9); index updates keep the exact
// select semantics (strict <, lowest index wins ties).
__device__ __forceinline__ void insdi(float d, int i,
                                      float& D1, int& I1, float& D2, int& I2,
                                      float& D3, int& I3) {
    const bool q1 = d < D1, q2 = d < D2, q3 = d < D3;
    I3 = q2 ? I2 : (q3 ? i : I3);
    I2 = q1 ? I1 : (q2 ? i : I2);
    I1 = q1 ? i : I1;
    D3 = __builtin_amdgcn_fmed3f(d, D2, D3);
    D2 = __builtin_amdgcn_fmed3f(d, D1, D2);
    D1 = fminf(d, D1);
}

// ------------------------------------------------- phase0 (fused front-end)
// blocks [0,1024)        : knn3 -- 64 queries/block, 8 waves x 256 knowns,
//                          4 contiguous 64-wide chains/wave, LDS merge.
//                          r10: sort key d' = -2 q.k + |k|^2 (3 FMAs/pair;
//                          monotone shift of d). Weights recomputed from
//                          EXACT distances for the 3 winners (bit-identical
//                          formula to r9 -> same weight values).
// blocks [1024,3072)     : kf->kfT transpose, two 32x32 tiles per block.
// blocks [3072,3328)     : W1/W2 -> bf16 cast; 128 blocks per W.
// block  3328            : BN scale/shift prep.
__global__ __launch_bounds__(512) void phase0(
    const float* __restrict__ unknown, const float* __restrict__ known,
    int* __restrict__ idx3, float* __restrict__ w3,
    const float* __restrict__ kf, float* __restrict__ kfT,
    const float* __restrict__ W1, const float* __restrict__ W2,
    bf16_t* __restrict__ Wc1, bf16_t* __restrict__ Wc2,
    const float* g1, const float* b1, const float* m1, const float* v1,
    const float* g2, const float* b2, const float* m2, const float* v2,
    float* s1, float* t1, float* s2, float* t2)
{
    __shared__ __align__(16) char smem[45056];
    const int bx = blockIdx.x;
    const int tid = threadIdx.x;

    if (bx < 1024) {
        // ------------------------------------------------------------ knn3
        float4* kp = (float4*)smem;                                  // 32 KB
        float (*md)[64][3] = (float(*)[64][3])(smem + 32768);        // 6 KB
        int   (*mi)[64][3] = (int(*)[64][3])(smem + 32768 + 6144);   // 6 KB
        const int b = bx >> 7;
        const int px = bx & 127;
        const int lane = tid & 63;
        const int wv = tid >> 6;                 // 0..7

        const size_t kb = (size_t)b * 2048 * 3;
        for (int t = tid; t < 2048; t += 512) {
            const float kx = known[kb + t * 3 + 0];
            const float ky = known[kb + t * 3 + 1];
            const float kz = known[kb + t * 3 + 2];
            const float kw = __fadd_rn(__fadd_rn(__fmul_rn(kx, kx),
                                                 __fmul_rn(ky, ky)),
                                       __fmul_rn(kz, kz));
            kp[t] = make_float4(kx, ky, kz, kw);
        }
        __syncthreads();

        const int p = px * 64 + lane;
        const size_t qo = ((size_t)b * 8192 + p) * 3;
        const float qx = unknown[qo + 0];
        const float qy = unknown[qo + 1];
        const float qz = unknown[qo + 2];
        const float nqx = -2.0f * qx;
        const float nqy = -2.0f * qy;
        const float nqz = -2.0f * qz;

        float d1[4], d2[4], d3[4];
        int   i1[4], i2[4], i3[4];
#pragma unroll
        for (int c = 0; c < 4; ++c) {
            d1[c] = 1e30f; d2[c] = 1e30f; d3[c] = 1e30f;
            i1[c] = 0;     i2[c] = 0;     i3[c] = 0;
        }

        const int jb = wv * 256;
#pragma unroll 2
        for (int t = 0; t < 64; ++t) {
#pragma unroll
            for (int c = 0; c < 4; ++c) {
                const int j = jb + c * 64 + t;   // chain c: contiguous block
                float4 k = kp[j];
                // d' = -2 q.k + |k|^2  (= d - |q|^2, monotone in d)
                float dp = __builtin_fmaf(nqx, k.x,
                           __builtin_fmaf(nqy, k.y,
                           __builtin_fmaf(nqz, k.z, k.w)));
                insdi(dp, j, d1[c], i1[c], d2[c], i2[c], d3[c], i3[c]);
            }
        }
        // merge 4 chains (ascending index ranges) -> wave-local top3
        float D1 = d1[0], D2 = d2[0], D3 = d3[0];
        int   I1 = i1[0], I2 = i2[0], I3 = i3[0];
#pragma unroll
        for (int c = 1; c < 4; ++c) {
            insdi(d1[c], i1[c], D1, I1, D2, I2, D3, I3);
            insdi(d2[c], i2[c], D1, I1, D2, I2, D3, I3);
            insdi(d3[c], i3[c], D1, I1, D2, I2, D3, I3);
        }
        md[wv][lane][0] = D1; md[wv][lane][1] = D2; md[wv][lane][2] = D3;
        mi[wv][lane][0] = I1; mi[wv][lane][1] = I2; mi[wv][lane][2] = I3;
        __syncthreads();

        if (tid < 64) {
            float F1 = md[0][tid][0], F2 = md[0][tid][1], F3 = md[0][tid][2];
            int   J1 = mi[0][tid][0], J2 = mi[0][tid][1], J3 = mi[0][tid][2];
#pragma unroll
            for (int w = 1; w < 8; ++w) {
                insdi(md[w][tid][0], mi[w][tid][0], F1, J1, F2, J2, F3, J3);
                insdi(md[w][tid][1], mi[w][tid][1], F1, J1, F2, J2, F3, J3);
                insdi(md[w][tid][2], mi[w][tid][2], F1, J1, F2, J2, F3, J3);
            }
            // recompute EXACT squared distances for the winners (bit-identical
            // to the r9 formula -> identical weights)
            const float4 ka = kp[J1];
            const float4 kb2 = kp[J2];
            const float4 kc = kp[J3];
            float ax = __fsub_rn(qx, ka.x), ay = __fsub_rn(qy, ka.y), az = __fsub_rn(qz, ka.z);
            float bx2 = __fsub_rn(qx, kb2.x), by = __fsub_rn(qy, kb2.y), bz = __fsub_rn(qz, kb2.z);
            float cx = __fsub_rn(qx, kc.x), cy = __fsub_rn(qy, kc.y), cz = __fsub_rn(qz, kc.z);
            float e1 = __fadd_rn(__fadd_rn(__fmul_rn(ax, ax), __fmul_rn(ay, ay)), __fmul_rn(az, az));
            float e2 = __fadd_rn(__fadd_rn(__fmul_rn(bx2, bx2), __fmul_rn(by, by)), __fmul_rn(bz, bz));
            float e3 = __fadd_rn(__fadd_rn(__fmul_rn(cx, cx), __fmul_rn(cy, cy)), __fmul_rn(cz, cz));
            float r1 = __fdiv_rn(1.f, __fadd_rn(e1, 1e-8f));
            float r2 = __fdiv_rn(1.f, __fadd_rn(e2, 1e-8f));
            float r3 = __fdiv_rn(1.f, __fadd_rn(e3, 1e-8f));
            float s = __fadd_rn(__fadd_rn(r1, r2), r3);
            const int pp = px * 64 + tid;
            const size_t o = ((size_t)b * 8192 + pp) * 3;
            idx3[o + 0] = J1; idx3[o + 1] = J2; idx3[o + 2] = J3;
            w3[o + 0] = __fdiv_rn(r1, s);
            w3[o + 1] = __fdiv_rn(r2, s);
            w3[o + 2] = __fdiv_rn(r3, s);
        }
    } else if (bx < 3072) {
        // ------------------------------------------- kf -> kfT (two tiles)
        float (*tile)[32][33] = (float(*)[32][33])smem;
        const int u = bx - 1024;                 // 0..2047
        const int b = u >> 8;                    // 8
        const int rem = u & 255;
        const int ct = rem >> 5;                 // 8 c-tiles
        const int mt2 = rem & 31;                // 32 m-tile pairs
        const int s = tid >> 8;                  // sub-block 0/1
        const int t = tid & 255;
        const int m0 = (mt2 * 2 + s) * 32;
        const int c0 = ct * 32;
        const int tx = t & 31;
        const int ty = t >> 5;                   // 0..7
#pragma unroll
        for (int k = 0; k < 4; ++k) {
            const int c = c0 + ty + k * 8;
            tile[s][ty + k * 8][tx] = kf[((size_t)b * 256 + c) * 2048 + m0 + tx];
        }
        __syncthreads();
#pragma unroll
        for (int k = 0; k < 4; ++k) {
            const int m = m0 + ty + k * 8;
            kfT[((size_t)b * 2048 + m) * 256 + c0 + tx] = tile[s][tx][ty + k * 8];
        }
    } else if (bx < 3328) {
        // --------------------------------------------------- W -> bf16
        const int v = bx - 3072;                 // 0..255
        const float* Wsrc = (v < 128) ? W1 : W2;
        bf16_t* Wdst = (v < 128) ? Wc1 : Wc2;
        const size_t base = ((size_t)(v & 127) * 512 + tid) * 4;
        float4 w = *(const float4*)(Wsrc + base);
        unsigned int u0 = pack2(w.x, w.y);
        unsigned int u1 = pack2(w.z, w.w);
        *(uint2*)(Wdst + base) = make_uint2(u0, u1);
    } else {
        // --------------------------------------------------------- BN prep
        int i = tid;
        if (i < 512) {
            float s = __fdiv_rn(g1[i], __fsqrt_rn(__fadd_rn(v1[i], 1e-5f)));
            s1[i] = s;
            t1[i] = __fsub_rn(b1[i], __fmul_rn(m1[i], s));
            float q = __fdiv_rn(g2[i], __fsqrt_rn(__fadd_rn(v2[i], 1e-5f)));
            s2[i] = q;
            t2[i] = __fsub_rn(b2[i], __fmul_rn(m2[i], q));
        }
    }
}

// ------------------------------------- fused interp gather + uf transpose
__global__ __launch_bounds__(256) void interp_uf(
    const float* __restrict__ kfT, const int* __restrict__ idx3,
    const float* __restrict__ w3, const float* __restrict__ uf,
    bf16_t* __restrict__ XT, int b0, int p0, int P)
{
    __shared__ bf16_t tile[64][66];
    const int bl = blockIdx.y;
    const int bg = b0 + bl;
    const int gsplit = P >> 4;

    if ((int)blockIdx.x < gsplit) {
        const int pt = blockIdx.x * 16 + (threadIdx.x >> 4);
        const int ch = (threadIdx.x & 15) * 16;
        const int p = p0 + pt;

        const size_t ib = ((size_t)bg * 8192 + p) * 3;
        const int i0 = idx3[ib + 0] & 2047;
        const int i1 = idx3[ib + 1] & 2047;
        const int i2 = idx3[ib + 2] & 2047;
        const float w0 = w3[ib + 0], w1 = w3[ib + 1], w2 = w3[ib + 2];

        const float4* r0 = (const float4*)(kfT + ((size_t)bg * 2048 + i0) * 256 + ch);
        const float4* r1 = (const float4*)(kfT + ((size_t)bg * 2048 + i1) * 256 + ch);
        const float4* r2 = (const float4*)(kfT + ((size_t)bg * 2048 + i2) * 256 + ch);

        unsigned int u[8];
#pragma unroll
        for (int q = 0; q < 4; ++q) {
            float4 a = r0[q], bv = r1[q], c = r2[q];
            float v0 = w0 * a.x + w1 * bv.x + w2 * c.x;
            float v1 = w0 * a.y + w1 * bv.y + w2 * c.y;
            float v2 = w0 * a.z + w1 * bv.z + w2 * c.z;
            float v3 = w0 * a.w + w1 * bv.w + w2 * c.w;
            u[q * 2 + 0] = pack2(v0, v1);
            u[q * 2 + 1] = pack2(v2, v3);
        }
        uint4* dst = (uint4*)(XT + ((size_t)bl * P + pt) * 512 + ch);
        dst[0] = make_uint4(u[0], u[1], u[2], u[3]);
        dst[1] = make_uint4(u[4], u[5], u[6], u[7]);
    } else {
        const int u2 = blockIdx.x - gsplit;
        const int c0 = (u2 & 3) * 64;        // 0,64,128,192
        const int pc = (u2 >> 2) * 64;
        const int tid = threadIdx.x;
        const int pl = tid & 63;
        const int grp = tid >> 6;
        const int p = p0 + pc + pl;

#pragma unroll
        for (int cc = 0; cc < 16; ++cc) {
            const int lc = grp * 16 + cc;
            tile[lc][pl] = (bf16_t)uf[((size_t)bg * 256 + c0 + lc) * 8192 + p];
        }
        __syncthreads();

        const int pr = tid >> 2;
        const int cs = (tid & 3) * 16;
        unsigned int u[8];
#pragma unroll
        for (int q = 0; q < 8; ++q) {
            unsigned short lo = __builtin_bit_cast(unsigned short, tile[cs + 2 * q + 0][pr]);
            unsigned short hi = __builtin_bit_cast(unsigned short, tile[cs + 2 * q + 1][pr]);
            u[q] = (unsigned int)lo | ((unsigned int)hi << 16);
        }
        uint4* dst = (uint4*)(XT + ((size_t)bl * P + pc + pr) * 512 + 256 + c0 + cs);
        dst[0] = make_uint4(u[0], u[1], u[2], u[3]);
        dst[1] = make_uint4(u[4], u[5], u[6], u[7]);
    }
}

// --------------------------------------------------------------- GEMM + BN + ReLU
// D = A(M,K=512) x BT(Nrows,K=512)^T.
// XCD mapping (field-proven r7): x = point-tile, gridDim.x % 8 == 0 -> the 4
// blocks sharing a point-tile land on the same XCD L2.
// BK=64, row-XOR swizzle chunk^=(row&7) both sides (field-proven r9).
template <bool CHAN_IS_M, bool F32_OUT>
__global__ __launch_bounds__(256) void gemm_bt_bn_relu(
    const bf16_t* __restrict__ A, const bf16_t* __restrict__ BT,
    void* __restrict__ Cv,
    const float* __restrict__ scale, const float* __restrict__ shift,
    int ldC, size_t strideA, size_t strideB, size_t strideC, size_t cofs)
{
    __shared__ __align__(16) bf16_t As[128 * 64];
    __shared__ __align__(16) bf16_t Bs[128 * 64];

    const int b = blockIdx.z;
    const size_t cbase = cofs + (size_t)b * strideC;

    const int m0 = (CHAN_IS_M ? blockIdx.y : blockIdx.x) * 128;
    const int n0 = (CHAN_IS_M ? blockIdx.x : blockIdx.y) * 128;
    const bf16_t* Ab = A + (size_t)b * strideA + (size_t)m0 * 512;
    const bf16_t* Bb = BT + (size_t)b * strideB + (size_t)n0 * 512;

    const int tid = threadIdx.x;
    const int lane = tid & 63;
    const int wave = tid >> 6;
    const int wm = (wave & 1) * 64;
    const int wn = (wave >> 1) * 64;

    // staging: 1024 16B chunks per matrix per K-step; thread covers chunks
    // tid, tid+256, tid+512, tid+768 (LDS-linear). Global chunk col XORed.
    size_t goff[4];
#pragma unroll
    for (int q = 0; q < 4; ++q) {
        const int ck = tid + q * 256;
        const int row = ck >> 3;
        const int c = ck & 7;
        goff[q] = (size_t)row * 512 + (size_t)((c ^ (row & 7)) * 8);
    }

    const int row_a = lane & 15;
    const int kq = lane >> 4;                    // 16B chunk 0..3 within half
    const int rsw = row_a & 7;
    const int col = lane & 15;
    const int rbase = (lane >> 4) * 4;

    f32x4 acc[4][4] = {};

    for (int kt = 0; kt < 512; kt += 64) {
#pragma unroll
        for (int q = 0; q < 4; ++q) {
            gload_lds16(Ab + goff[q] + kt, As + (size_t)(tid + q * 256) * 8);
            gload_lds16(Bb + goff[q] + kt, Bs + (size_t)(tid + q * 256) * 8);
        }
        __builtin_amdgcn_s_waitcnt(0);
        __syncthreads();

#pragma unroll
        for (int h = 0; h < 2; ++h) {
            const int csel = ((h * 4 + kq) ^ rsw) * 8;   // element offset in row
            bf16x8 af[4], bfr[4];
#pragma unroll
            for (int i = 0; i < 4; ++i)
                af[i] = *(const bf16x8*)(As + (size_t)(wm + i * 16 + row_a) * 64 + csel);
#pragma unroll
            for (int j = 0; j < 4; ++j)
                bfr[j] = *(const bf16x8*)(Bs + (size_t)(wn + j * 16 + row_a) * 64 + csel);
#pragma unroll
            for (int i = 0; i < 4; ++i)
#pragma unroll
                for (int j = 0; j < 4; ++j)
                    acc[i][j] = __builtin_amdgcn_mfma_f32_16x16x32_bf16(
                        af[i], bfr[j], acc[i][j], 0, 0, 0);
        }
        __syncthreads();
    }

#pragma unroll
    for (int i = 0; i < 4; ++i) {
#pragma unroll
        for (int j = 0; j < 4; ++j) {
            const int mb = m0 + wm + i * 16 + rbase;
            const int nn = n0 + wn + j * 16 + col;
            float sc = 0.f, sh = 0.f;
            if (!CHAN_IS_M) { sc = scale[nn]; sh = shift[nn]; }
#pragma unroll
            for (int r = 0; r < 4; ++r) {
                const int mm = mb + r;
                float s = CHAN_IS_M ? scale[mm] : sc;
                float t = CHAN_IS_M ? shift[mm] : sh;
                float v = fmaxf(acc[i][j][r] * s + t, 0.0f);
                const size_t ci = cbase + (size_t)mm * (size_t)ldC + nn;
                if (F32_OUT) {
                    // output is never re-read -> keep it out of L2
                    __builtin_nontemporal_store(v, (float*)Cv + ci);
                } else {
                    ((bf16_t*)Cv)[ci] = (bf16_t)v;
                }
            }
        }
    }
}

// ---------------------------------------------------------------- launch
extern "C" void kernel_launch(void* const* d_in, const int* in_sizes, int n_in,
                              void* d_out, int out_size, void* d_ws, size_t ws_size,
                              hipStream_t stream) {
    (void)in_sizes; (void)n_in; (void)out_size;
    const float* unknown  = (const float*)d_in[0];
    const float* known    = (const float*)d_in[1];
    const float* unknow_f = (const float*)d_in[2];
    const float* known_f  = (const float*)d_in[3];
    const float* W1       = (const float*)d_in[4];
    const float* g1 = (const float*)d_in[5]; const float* b1 = (const float*)d_in[6];
    const float* m1 = (const float*)d_in[7]; const float* v1 = (const float*)d_in[8];
    const float* W2       = (const float*)d_in[9];
    const float* g2 = (const float*)d_in[10]; const float* b2 = (const float*)d_in[11];
    const float* m2 = (const float*)d_in[12]; const float* v2 = (const float*)d_in[13];

    char* ws = (char*)d_ws;
    float* s1 = (float*)(ws + 0);
    float* t1 = s1 + 512;
    float* s2 = s1 + 1024;
    float* t2 = s1 + 1536;
    int*    idx3 = (int*)(ws + 16384);                 // 768 KB
    float*  w3   = (float*)(ws + 16384 + 786432);      // 768 KB -> ends 1589248
    bf16_t* Wc1  = (bf16_t*)(ws + 1589248);            // 512 KB
    bf16_t* Wc2  = (bf16_t*)(ws + 2113536);            // 512 KB -> ends 2637824
    float*  kfT  = (float*)(ws + (3u << 20));          // 16 MB (8,2048,256) f32
    const size_t FIXED = 20u << 20;                    // 20 MB fixed region

    // scratch tiers: XT+HT cost 2048 B per (batch,point)
    size_t avail = (ws_size > FIXED) ? (ws_size - FIXED) : 0;
    size_t pts = avail / 2048;
    int nb, P;
    if (pts >= 65536)      { nb = 8; P = 8192; }
    else if (pts >= 8192)  { nb = (int)(pts / 8192); P = 8192; }
    else {
        nb = 1;
        P = (int)((pts / 128) * 128);
        if (P < 128) P = 128;
        if (P > 8192) P = 8192;
    }
    bf16_t* XT = (bf16_t*)(ws + FIXED);
    bf16_t* HT = XT + (size_t)nb * P * 512;

    phase0<<<3329, 512, 0, stream>>>(unknown, known, idx3, w3,
                                     known_f, kfT, W1, W2, Wc1, Wc2,
                                     g1, b1, m1, v1, g2, b2, m2, v2,
                                     s1, t1, s2, t2);

    for (int b0 = 0; b0 < 8; b0 += nb) {
        const int cur = (8 - b0 < nb) ? (8 - b0) : nb;
        for (int p0 = 0; p0 < 8192; p0 += P) {
            const int cp = (8192 - p0 < P) ? (8192 - p0) : P;

            interp_uf<<<dim3(cp / 8, cur), 256, 0, stream>>>(
                kfT, idx3, w3, unknow_f, XT, b0, p0, cp);

            // GEMM1: HT[p][o] = relu(s1[o]*(XT x Wc1^T)+t1[o]); bf16 out
            gemm_bt_bn_relu<false, false><<<dim3(cp / 128, 4, cur), 256, 0, stream>>>(
                XT, Wc1, HT, s1, t1, 512,
                (size_t)cp * 512, (size_t)0, (size_t)cp * 512, (size_t)0);

            // GEMM2: OUT[o][p0+n] = relu(s2[o]*(Wc2 x HT^T)+t2[o]); f32 out
            gemm_bt_bn_relu<true, true><<<dim3(cp / 128, 4, cur), 256, 0, stream>>>(
                Wc2, HT, d_out, s2, t2, 8192,
                (size_t)0, (size_t)cp * 512, (size_t)512 * 8192,
                (size_t)b0 * 512 * 8192 + p0);
        }
    }
}